// Round 25
// baseline (460.046 us; speedup 1.0000x reference)
//
#include <hip/hip_runtime.h>

typedef __attribute__((ext_vector_type(8))) short short8;
typedef __attribute__((ext_vector_type(4))) short short4v;
typedef __attribute__((ext_vector_type(4))) float f32x4;

__device__ inline short f2bf(float f) {
    union { float f; unsigned u; } v; v.f = f;
    unsigned r = v.u + 0x7fffu + ((v.u >> 16) & 1u);
    return (short)(r >> 16);
}

__device__ __forceinline__ void gload16(const short* g, short* l) {
    __builtin_amdgcn_global_load_lds(
        (const __attribute__((address_space(1))) unsigned int*)g,
        (__attribute__((address_space(3))) unsigned int*)l, 16, 0, 0);
}

// ---------------- elementwise f32 -> bf16 ----------------
__global__ __launch_bounds__(256) void cvt_f32_to_bf16(const float* __restrict__ in,
                                                       short* __restrict__ out, int n4) {
    int i = blockIdx.x * 256 + threadIdx.x;
    if (i >= n4) return;
    float4 v = ((const float4*)in)[i];
    short4v o;
    o[0] = f2bf(v.x); o[1] = f2bf(v.y); o[2] = f2bf(v.z); o[3] = f2bf(v.w);
    ((short4v*)out)[i] = o;
}

// ---------------- tiled transpose (R x C) f32 -> bf16 (C x R) ----------------
__global__ __launch_bounds__(256) void transpose_to_bf16(const float* __restrict__ in,
                                                         short* __restrict__ out,
                                                         int R, int C) {
    __shared__ short tile[64][66];
    int r0 = blockIdx.x * 64, c0 = blockIdx.y * 64;
    int tid = threadIdx.x;
#pragma unroll
    for (int i = 0; i < 16; i++) {
        int idx = i * 256 + tid;
        int r = idx >> 6, c = idx & 63;
        tile[r][c] = f2bf(in[(size_t)(r0 + r) * C + (c0 + c)]);
    }
    __syncthreads();
#pragma unroll
    for (int i = 0; i < 16; i++) {
        int idx = i * 256 + tid;
        int c = idx >> 6, r = idx & 63;
        out[(size_t)(c0 + c) * R + (r0 + r)] = tile[r][c];
    }
}

// ======== bf16 GEMM 256x256, BK=32, 4-buf depth-3 + REGISTER FRAGMENT PREFETCH ====
// r24 skeleton + in-wave LDS||MFMA overlap: at iter t, tile-(t+1)'s 12 ds_reads
// issue into the ALTERNATE named fragment set (x2 unroll -> static indexing),
// then tile-t's 32 MFMAs run from the current set. No dependency -> compiler's
// counted lgkmcnt lets ds_reads flow under MFMAs (r24 arithmetic: wall 2690cy
// = LDS 1130 + MFMA 1030 serialized; overlapped floor ~1700cy).
// Ledger: end-of-t waits vmcnt(4) = tile t+2 retired (needed by t+1's prefetch);
// t+3 stays in flight (load-to-use >= 1.5 tiles ~ 3000cy > 900cy HBM latency).
// WAR: buf[(t+3)&3] last ds_read at t-2's prefetch, consumed by t-1's MFMA
// (register dep) before t-1's end barrier < stage at t.
// Registers: 128 AGPR acc + 2x48 VGPR frags + addr ~ 245 << 1024/wave budget
// (128KB LDS -> 1 block/CU -> 2 waves/SIMD). NT must be even (K=2048 -> 64).
template <int EPI>
__global__ __launch_bounds__(512) void gemm256(const short* __restrict__ A,
                                               const short* __restrict__ Bt,
                                               int M, int N, int K,
                                               short* __restrict__ O0, short* __restrict__ O1,
                                               short* __restrict__ O2, float* __restrict__ OF,
                                               float qscale) {
    __shared__ short As[4][256 * 32];
    __shared__ short Bs[4][256 * 32];
    int tid = threadIdx.x, lane = tid & 63, wid = tid >> 6;
    int wr = wid >> 2, wc = wid & 3;
    int mtn = M >> 8;
    int band = mtn >> 3;
    int bid = blockIdx.x;
    int xcd = bid & 7, kk = bid >> 3;
    int nt = kk / band, gmr = kk % band;
    int mt = xcd * band + gmr;
    int row0 = mt << 8, col0 = nt << 8;
    int t15 = lane & 15, t4 = lane >> 4;
    int NT = K >> 5;

    f32x4 acc[8][4];
#pragma unroll
    for (int m = 0; m < 8; m++)
#pragma unroll
        for (int n = 0; n < 4; n++) acc[m][n] = (f32x4){0.f, 0.f, 0.f, 0.f};

    int sg = (lane & 3) ^ ((lane >> 3) & 3);
    int srw = lane >> 2;
    int ce = t4 ^ ((t15 >> 1) & 3);

    auto stageA = [&](int t) {
        if (t >= NT) return;
        int kb = t << 5;
        short* dst = &As[t & 3][0];
#pragma unroll
        for (int i = 0; i < 2; i++) {
            int seg = wid * 2 + i;
            int row = seg * 16 + srw;
            gload16(A + (size_t)(row0 + row) * K + kb + sg * 8, dst + seg * 512);
        }
    };
    auto stageB = [&](int t) {
        if (t >= NT) return;
        int kb = t << 5;
        short* dst = &Bs[t & 3][0];
#pragma unroll
        for (int i = 0; i < 2; i++) {
            int seg = wid * 2 + i;
            int row = seg * 16 + srw;
            gload16(Bt + (size_t)(col0 + row) * K + kb + sg * 8, dst + seg * 512);
        }
    };

    auto lda = [&](int bufi, short8 (&af)[8]) {
#pragma unroll
        for (int m = 0; m < 8; m++) {
            int row = wr * 128 + m * 16 + t15;
            af[m] = *(short8*)(&As[bufi][row * 32 + ce * 8]);
        }
    };
    auto ldb = [&](int bufi, short8 (&bf)[4]) {
#pragma unroll
        for (int n = 0; n < 4; n++) {
            int row = wc * 64 + n * 16 + t15;
            bf[n] = *(short8*)(&Bs[bufi][row * 32 + ce * 8]);
        }
    };

#define MFMA32(AF, BF)                                                               \
    __builtin_amdgcn_s_setprio(1);                                                   \
    _Pragma("unroll")                                                                \
    for (int m_ = 0; m_ < 8; m_++)                                                   \
        _Pragma("unroll")                                                            \
        for (int n_ = 0; n_ < 4; n_++)                                               \
            acc[m_][n_] = __builtin_amdgcn_mfma_f32_16x16x32_bf16(                   \
                AF[m_], BF[n_], acc[m_][n_], 0, 0, 0);                               \
    __builtin_amdgcn_s_setprio(0);

    // prologue: stage 0,1,2; retire 0,1 (vmcnt(4)); barrier; load tile-0 frags
    stageA(0); stageB(0);
    stageA(1); stageB(1);
    stageA(2); stageB(2);
    asm volatile("s_waitcnt vmcnt(4)" ::: "memory");
    asm volatile("s_barrier" ::: "memory");

    short8 a0[8], b0[4], a1[8], b1[4];
    lda(0, a0); ldb(0, b0);

    for (int t = 0; t < NT; t += 2) {
        // --- iter t: compute a0/b0, prefetch (t+1) into a1/b1 ---
        stageA(t + 3); stageB(t + 3);
        if (t + 1 < NT) { lda((t + 1) & 3, a1); ldb((t + 1) & 3, b1); }
        MFMA32(a0, b0);
        if (t + 3 < NT) asm volatile("s_waitcnt vmcnt(4)" ::: "memory");
        else            asm volatile("s_waitcnt vmcnt(0)" ::: "memory");
        asm volatile("s_barrier" ::: "memory");
        // --- iter t+1: compute a1/b1, prefetch (t+2) into a0/b0 ---
        stageA(t + 4); stageB(t + 4);
        if (t + 2 < NT) { lda((t + 2) & 3, a0); ldb((t + 2) & 3, b0); }
        MFMA32(a1, b1);
        if (t + 4 < NT) asm volatile("s_waitcnt vmcnt(4)" ::: "memory");
        else            asm volatile("s_waitcnt vmcnt(0)" ::: "memory");
        asm volatile("s_barrier" ::: "memory");
    }

#undef MFMA32

#pragma unroll
    for (int m = 0; m < 8; m++) {
#pragma unroll
        for (int n = 0; n < 4; n++) {
#pragma unroll
            for (int r = 0; r < 4; r++) {
                float v = acc[m][n][r];
                int gm2 = row0 + wr * 128 + m * 16 + t4 * 4 + r;
                int gn = col0 + wc * 64 + n * 16 + t15;
                if (EPI == 0) {
                    int part = gn >> 11, within = gn & 2047;
                    int h = within >> 7, dk = within & 127;
                    int bb = gm2 >> 11, s = gm2 & 2047;
                    int z = bb * 16 + h;
                    if (part == 0) O0[((size_t)z * 2048 + s) * 128 + dk] = f2bf(v * qscale);
                    else if (part == 1) O1[((size_t)z * 2048 + s) * 128 + dk] = f2bf(v);
                    else O2[((size_t)z * 128 + dk) * 2048 + s] = f2bf(v);  // V transposed
                } else {
                    OF[(size_t)gm2 * N + gn] = v;
                }
            }
        }
    }
}

// ---------------- causal flash attention: paired panels + counted-vmcnt (r20 proven) ----
__global__ __launch_bounds__(512, 4) void attn_fwd(const short* __restrict__ Q,
                                                   const short* __restrict__ Kb,
                                                   const short* __restrict__ Vt,
                                                   short* __restrict__ O) {
    __shared__ short Kls[2][64 * 128];
    __shared__ short Vls[128 * 64];
    __shared__ __align__(16) short Pls[8][16 * 64];
    int tid = threadIdx.x, lane = tid & 63, wid = tid >> 6;
    int bx = blockIdx.x, z = blockIdx.y;
    int pr = bx >> 1, hh = bx & 1;
    int qpan = (wid < 4) ? pr : (15 - pr);
    int t15 = lane & 15, t4 = lane >> 4;
    const short* Qh = Q + (size_t)z * 2048 * 128;
    const short* Kh = Kb + (size_t)z * 2048 * 128;
    const short* Vh = Vt + (size_t)z * 128 * 2048;
    int q0w = qpan * 128 + hh * 64 + (wid & 3) * 16;

    short8 qf[4];
    {
        const short* qrow = Qh + (size_t)(q0w + t15) * 128;
#pragma unroll
        for (int s = 0; s < 4; s++) qf[s] = *(const short8*)(qrow + s * 32 + t4 * 8);
    }

    f32x4 o[8];
#pragma unroll
    for (int st = 0; st < 8; st++) o[st] = (f32x4){0.f, 0.f, 0.f, 0.f};
    float m_s = -1e30f, l_s = 0.f;

    auto stageK = [&](int t, int buf) {
#pragma unroll
        for (int i = 0; i < 2; i++) {
            int seg = wid * 2 + i;
            int row = seg * 4 + t4;
            int kl = (lane & 15) ^ (row & 7);
            gload16(Kh + (size_t)(t * 64 + row) * 128 + kl * 8, &Kls[buf][seg * 512]);
        }
    };
    auto stageV = [&](int t) {
#pragma unroll
        for (int i = 0; i < 2; i++) {
            int seg = wid * 2 + i;
            int row = seg * 8 + (lane >> 3);
            int kl = (lane & 7) ^ (row & 7);
            gload16(Vh + (size_t)row * 2048 + t * 64 + kl * 8, &Vls[seg * 512]);
        }
    };

    int nt = 2 * (15 - pr) + 2;
    stageK(0, 0);
    __syncthreads();

    for (int t = 0; t < nt; t++) {
        int buf = t & 1;
        stageV(t);
        if (t + 1 < nt) stageK(t + 1, buf ^ 1);
        bool active = (t * 64 <= q0w + 15);

        if (active) {
            f32x4 sc[4];
#pragma unroll
            for (int c = 0; c < 4; c++) {
                sc[c] = (f32x4){0.f, 0.f, 0.f, 0.f};
#pragma unroll
                for (int s = 0; s < 4; s++) {
                    int row = c * 16 + t15;
                    int ck = (s * 4 + t4) ^ (row & 7);
                    short8 kf = *(short8*)(&Kls[buf][row * 128 + ck * 8]);
                    sc[c] = __builtin_amdgcn_mfma_f32_16x16x32_bf16(kf, qf[s], sc[c], 0, 0, 0);
                }
            }

            if (t * 64 + 63 > q0w) {
                int qq = q0w + t15;
#pragma unroll
                for (int c = 0; c < 4; c++)
#pragma unroll
                    for (int r = 0; r < 4; r++) {
                        int kv = t * 64 + c * 16 + t4 * 4 + r;
                        if (kv > qq) sc[c][r] = -1e30f;
                    }
            }

            float tm = fmaxf(fmaxf(fmaxf(sc[0][0], sc[0][1]), fmaxf(sc[0][2], sc[0][3])),
                             fmaxf(fmaxf(sc[1][0], sc[1][1]), fmaxf(sc[1][2], sc[1][3])));
            tm = fmaxf(tm, fmaxf(fmaxf(fmaxf(sc[2][0], sc[2][1]), fmaxf(sc[2][2], sc[2][3])),
                                 fmaxf(fmaxf(sc[3][0], sc[3][1]), fmaxf(sc[3][2], sc[3][3]))));
            bool need = (tm > m_s + 8.f);
            if (__any(need)) {
                tm = fmaxf(tm, __shfl_xor(tm, 16));
                tm = fmaxf(tm, __shfl_xor(tm, 32));
                float mn = fmaxf(m_s, tm);
                float scf = exp2f(m_s - mn);
                m_s = mn;
                l_s *= scf;
                float sr0 = __shfl(scf, t4 * 4 + 0);
                float sr1 = __shfl(scf, t4 * 4 + 1);
                float sr2 = __shfl(scf, t4 * 4 + 2);
                float sr3 = __shfl(scf, t4 * 4 + 3);
#pragma unroll
                for (int st = 0; st < 8; st++) {
                    o[st][0] *= sr0; o[st][1] *= sr1;
                    o[st][2] *= sr2; o[st][3] *= sr3;
                }
            }
            int t15l = t15 & 7;
#pragma unroll
            for (int c = 0; c < 4; c++) {
                float p0 = exp2f(sc[c][0] - m_s);
                float p1 = exp2f(sc[c][1] - m_s);
                float p2 = exp2f(sc[c][2] - m_s);
                float p3 = exp2f(sc[c][3] - m_s);
                l_s += (p0 + p1) + (p2 + p3);
                unsigned u0, u1;
                asm("v_cvt_pk_bf16_f32 %0, %1, %2" : "=v"(u0) : "v"(p0), "v"(p1));
                asm("v_cvt_pk_bf16_f32 %0, %1, %2" : "=v"(u1) : "v"(p2), "v"(p3));
                int ch = (c * 2 + (t4 >> 1)) ^ t15l;
                uint2 uu; uu.x = u0; uu.y = u1;
                *(uint2*)((char*)&Pls[wid][0] + t15 * 128 + ch * 16 + (t4 & 1) * 8) = uu;
            }
        }

        if (t + 1 < nt) asm volatile("s_waitcnt vmcnt(2)" ::: "memory");
        else            asm volatile("s_waitcnt vmcnt(0)" ::: "memory");
        __builtin_amdgcn_s_barrier();

        if (active) {
            short8 pa[2];
#pragma unroll
            for (int s2 = 0; s2 < 2; s2++) {
                int ch2 = (s2 * 4 + t4) ^ (t15 & 7);
                pa[s2] = *(short8*)((char*)&Pls[wid][0] + t15 * 128 + ch2 * 16);
            }
#pragma unroll
            for (int st = 0; st < 8; st++) {
#pragma unroll
                for (int s2 = 0; s2 < 2; s2++) {
                    int row = st * 16 + t15;
                    int ck = (s2 * 4 + t4) ^ (row & 7);
                    short8 vf = *(short8*)(&Vls[row * 64 + ck * 8]);
                    o[st] = __builtin_amdgcn_mfma_f32_16x16x32_bf16(pa[s2], vf, o[st], 0, 0, 0);
                }
            }
        }

        asm volatile("s_waitcnt vmcnt(0)" ::: "memory");
        __builtin_amdgcn_s_barrier();
    }

    l_s += __shfl_xor(l_s, 16);
    l_s += __shfl_xor(l_s, 32);
    float lr0 = __shfl(l_s, t4 * 4 + 0);
    float lr1 = __shfl(l_s, t4 * 4 + 1);
    float lr2 = __shfl(l_s, t4 * 4 + 2);
    float lr3 = __shfl(l_s, t4 * 4 + 3);
    float lr[4] = {lr0, lr1, lr2, lr3};

    int b = z >> 4, h = z & 15;
#pragma unroll
    for (int st = 0; st < 8; st++)
#pragma unroll
        for (int r = 0; r < 4; r++) {
            int s = q0w + t4 * 4 + r;
            float val = o[st][r] / lr[r];
            O[((size_t)b * 2048 + s) * 2048 + h * 128 + st * 16 + t15] = f2bf(val);
        }
}

extern "C" void kernel_launch(void* const* d_in, const int* in_sizes, int n_in,
                              void* d_out, int out_size, void* d_ws, size_t ws_size,
                              hipStream_t stream) {
    const float* x = (const float*)d_in[0];      // (4,2048,2048)
    const float* Wqkv = (const float*)d_in[1];   // (2048,6144)
    const float* Wo = (const float*)d_in[2];     // (2048,2048)

    const int B = 4, S = 2048, D = 2048, DK = 128;
    const int M = B * S;          // 8192
    const int N1 = 3 * D;         // 6144
    (void)in_sizes; (void)n_in; (void)out_size; (void)ws_size;

    char* ws = (char*)d_ws;
    size_t off = 0;
    short* x_bf = (short*)(ws + off);   off += (size_t)M * D * 2;
    short* wqkv_t = (short*)(ws + off); off += (size_t)N1 * D * 2;
    short* wo_t = (short*)(ws + off);   off += (size_t)D * D * 2;
    short* Qb = (short*)(ws + off);     off += (size_t)64 * S * DK * 2;
    short* Kb = (short*)(ws + off);     off += (size_t)64 * S * DK * 2;
    short* Vt = (short*)(ws + off);     off += (size_t)64 * S * DK * 2;
    short* Ob = (short*)(ws + off);     off += (size_t)M * D * 2;

    // 1. x -> bf16
    cvt_f32_to_bf16<<<(M * D / 4 + 255) / 256, 256, 0, stream>>>(x, x_bf, M * D / 4);
    // 2. Wqkv^T -> bf16 (N1 x D)
    transpose_to_bf16<<<dim3(D / 64, N1 / 64, 1), 256, 0, stream>>>(Wqkv, wqkv_t, D, N1);
    // 3. Wo^T -> bf16 (D x D)
    transpose_to_bf16<<<dim3(D / 64, D / 64, 1), 256, 0, stream>>>(Wo, wo_t, D, D);
    // 4. GEMM1: qkv = x @ Wqkv -> Q(scaled 1/(sqrt(128)ln2))/K/V^T  (reg-prefetch depth-3)
    gemm256<0><<<(M / 256) * (N1 / 256), 512, 0, stream>>>(
        x_bf, wqkv_t, M, N1, D, Qb, Kb, Vt, nullptr, 0.12751743553366927f);
    // 5. attention (paired panels + counted-vmcnt barriers)
    attn_fwd<<<dim3(16, 64), 512, 0, stream>>>(Qb, Kb, Vt, Ob);
    // 6. GEMM2: out = O @ Wo (f32)   (reg-prefetch depth-3, 256 blocks)
    gemm256<1><<<(M / 256) * (D / 256), 512, 0, stream>>>(
        Ob, wo_t, M, D, D, nullptr, nullptr, nullptr, (float*)d_out, 1.0f);
}

// Round 26
// 435.317 us; speedup vs baseline: 1.0568x; 1.0568x over previous
//
#include <hip/hip_runtime.h>

typedef __attribute__((ext_vector_type(8))) short short8;
typedef __attribute__((ext_vector_type(4))) short short4v;
typedef __attribute__((ext_vector_type(4))) float f32x4;

__device__ inline short f2bf(float f) {
    union { float f; unsigned u; } v; v.f = f;
    unsigned r = v.u + 0x7fffu + ((v.u >> 16) & 1u);
    return (short)(r >> 16);
}

__device__ __forceinline__ void gload16(const short* g, short* l) {
    __builtin_amdgcn_global_load_lds(
        (const __attribute__((address_space(1))) unsigned int*)g,
        (__attribute__((address_space(3))) unsigned int*)l, 16, 0, 0);
}

// ---------------- elementwise f32 -> bf16 ----------------
__global__ __launch_bounds__(256) void cvt_f32_to_bf16(const float* __restrict__ in,
                                                       short* __restrict__ out, int n4) {
    int i = blockIdx.x * 256 + threadIdx.x;
    if (i >= n4) return;
    float4 v = ((const float4*)in)[i];
    short4v o;
    o[0] = f2bf(v.x); o[1] = f2bf(v.y); o[2] = f2bf(v.z); o[3] = f2bf(v.w);
    ((short4v*)out)[i] = o;
}

// ---------------- tiled transpose (R x C) f32 -> bf16 (C x R) ----------------
__global__ __launch_bounds__(256) void transpose_to_bf16(const float* __restrict__ in,
                                                         short* __restrict__ out,
                                                         int R, int C) {
    __shared__ short tile[64][66];
    int r0 = blockIdx.x * 64, c0 = blockIdx.y * 64;
    int tid = threadIdx.x;
#pragma unroll
    for (int i = 0; i < 16; i++) {
        int idx = i * 256 + tid;
        int r = idx >> 6, c = idx & 63;
        tile[r][c] = f2bf(in[(size_t)(r0 + r) * C + (c0 + c)]);
    }
    __syncthreads();
#pragma unroll
    for (int i = 0; i < 16; i++) {
        int idx = i * 256 + tid;
        int c = idx >> 6, r = idx & 63;
        out[(size_t)(c0 + c) * R + (r0 + r)] = tile[r][c];
    }
}

// ======== bf16 GEMM 256x256, BK=32, 4-buf depth-3 (r16/r20/r24 proven best) ====
template <int EPI>
__global__ __launch_bounds__(512) void gemm256(const short* __restrict__ A,
                                               const short* __restrict__ Bt,
                                               int M, int N, int K,
                                               short* __restrict__ O0, short* __restrict__ O1,
                                               short* __restrict__ O2, float* __restrict__ OF,
                                               float qscale) {
    __shared__ short As[4][256 * 32];
    __shared__ short Bs[4][256 * 32];
    int tid = threadIdx.x, lane = tid & 63, wid = tid >> 6;
    int wr = wid >> 2, wc = wid & 3;
    int mtn = M >> 8;
    int band = mtn >> 3;
    int bid = blockIdx.x;
    int xcd = bid & 7, kk = bid >> 3;
    int nt = kk / band, gmr = kk % band;
    int mt = xcd * band + gmr;
    int row0 = mt << 8, col0 = nt << 8;
    int t15 = lane & 15, t4 = lane >> 4;
    int NT = K >> 5;

    f32x4 acc[8][4];
#pragma unroll
    for (int m = 0; m < 8; m++)
#pragma unroll
        for (int n = 0; n < 4; n++) acc[m][n] = (f32x4){0.f, 0.f, 0.f, 0.f};

    int sg = (lane & 3) ^ ((lane >> 3) & 3);
    int srw = lane >> 2;
    int ce = t4 ^ ((t15 >> 1) & 3);

    auto stageA = [&](int t) {
        if (t >= NT) return;
        int kb = t << 5;
        short* dst = &As[t & 3][0];
#pragma unroll
        for (int i = 0; i < 2; i++) {
            int seg = wid * 2 + i;
            int row = seg * 16 + srw;
            gload16(A + (size_t)(row0 + row) * K + kb + sg * 8, dst + seg * 512);
        }
    };
    auto stageB = [&](int t) {
        if (t >= NT) return;
        int kb = t << 5;
        short* dst = &Bs[t & 3][0];
#pragma unroll
        for (int i = 0; i < 2; i++) {
            int seg = wid * 2 + i;
            int row = seg * 16 + srw;
            gload16(Bt + (size_t)(col0 + row) * K + kb + sg * 8, dst + seg * 512);
        }
    };

    stageA(0); stageB(0);
    stageA(1); stageB(1);
    stageA(2); stageB(2);
    asm volatile("s_waitcnt vmcnt(8)" ::: "memory");
    asm volatile("s_barrier" ::: "memory");

    for (int t = 0; t < NT; t++) {
        int bufi = t & 3;
        short8 af[8], bf[4];
#pragma unroll
        for (int m = 0; m < 8; m++) {
            int row = wr * 128 + m * 16 + t15;
            af[m] = *(short8*)(&As[bufi][row * 32 + ce * 8]);
        }
#pragma unroll
        for (int n = 0; n < 4; n++) {
            int row = wc * 64 + n * 16 + t15;
            bf[n] = *(short8*)(&Bs[bufi][row * 32 + ce * 8]);
        }
        stageA(t + 3); stageB(t + 3);

        __builtin_amdgcn_s_setprio(1);
#pragma unroll
        for (int m = 0; m < 8; m++)
#pragma unroll
            for (int n = 0; n < 4; n++)
                acc[m][n] = __builtin_amdgcn_mfma_f32_16x16x32_bf16(af[m], bf[n], acc[m][n], 0, 0, 0);
        __builtin_amdgcn_s_setprio(0);

        if (t + 3 < NT)       asm volatile("s_waitcnt vmcnt(8)" ::: "memory");
        else if (t + 3 == NT) asm volatile("s_waitcnt vmcnt(4)" ::: "memory");
        else                  asm volatile("s_waitcnt vmcnt(0)" ::: "memory");
        asm volatile("s_barrier" ::: "memory");
    }

#pragma unroll
    for (int m = 0; m < 8; m++) {
#pragma unroll
        for (int n = 0; n < 4; n++) {
#pragma unroll
            for (int r = 0; r < 4; r++) {
                float v = acc[m][n][r];
                int gm2 = row0 + wr * 128 + m * 16 + t4 * 4 + r;
                int gn = col0 + wc * 64 + n * 16 + t15;
                if (EPI == 0) {
                    int part = gn >> 11, within = gn & 2047;
                    int h = within >> 7, dk = within & 127;
                    int bb = gm2 >> 11, s = gm2 & 2047;
                    int z = bb * 16 + h;
                    if (part == 0) O0[((size_t)z * 2048 + s) * 128 + dk] = f2bf(v * qscale);
                    else if (part == 1) O1[((size_t)z * 2048 + s) * 128 + dk] = f2bf(v);
                    else O2[((size_t)z * 128 + dk) * 2048 + s] = f2bf(v);  // V transposed
                } else {
                    OF[(size_t)gm2 * N + gn] = v;
                }
            }
        }
    }
}

// ---------------- causal flash attention: paired panels + counted-vmcnt (r20 proven) ----
__global__ __launch_bounds__(512, 4) void attn_fwd(const short* __restrict__ Q,
                                                   const short* __restrict__ Kb,
                                                   const short* __restrict__ Vt,
                                                   short* __restrict__ O) {
    __shared__ short Kls[2][64 * 128];
    __shared__ short Vls[128 * 64];
    __shared__ __align__(16) short Pls[8][16 * 64];
    int tid = threadIdx.x, lane = tid & 63, wid = tid >> 6;
    int bx = blockIdx.x, z = blockIdx.y;
    int pr = bx >> 1, hh = bx & 1;
    int qpan = (wid < 4) ? pr : (15 - pr);
    int t15 = lane & 15, t4 = lane >> 4;
    const short* Qh = Q + (size_t)z * 2048 * 128;
    const short* Kh = Kb + (size_t)z * 2048 * 128;
    const short* Vh = Vt + (size_t)z * 128 * 2048;
    int q0w = qpan * 128 + hh * 64 + (wid & 3) * 16;

    short8 qf[4];
    {
        const short* qrow = Qh + (size_t)(q0w + t15) * 128;
#pragma unroll
        for (int s = 0; s < 4; s++) qf[s] = *(const short8*)(qrow + s * 32 + t4 * 8);
    }

    f32x4 o[8];
#pragma unroll
    for (int st = 0; st < 8; st++) o[st] = (f32x4){0.f, 0.f, 0.f, 0.f};
    float m_s = -1e30f, l_s = 0.f;

    auto stageK = [&](int t, int buf) {
#pragma unroll
        for (int i = 0; i < 2; i++) {
            int seg = wid * 2 + i;
            int row = seg * 4 + t4;
            int kl = (lane & 15) ^ (row & 7);
            gload16(Kh + (size_t)(t * 64 + row) * 128 + kl * 8, &Kls[buf][seg * 512]);
        }
    };
    auto stageV = [&](int t) {
#pragma unroll
        for (int i = 0; i < 2; i++) {
            int seg = wid * 2 + i;
            int row = seg * 8 + (lane >> 3);
            int kl = (lane & 7) ^ (row & 7);
            gload16(Vh + (size_t)row * 2048 + t * 64 + kl * 8, &Vls[seg * 512]);
        }
    };

    int nt = 2 * (15 - pr) + 2;
    stageK(0, 0);
    __syncthreads();

    for (int t = 0; t < nt; t++) {
        int buf = t & 1;
        stageV(t);
        if (t + 1 < nt) stageK(t + 1, buf ^ 1);
        bool active = (t * 64 <= q0w + 15);

        if (active) {
            f32x4 sc[4];
#pragma unroll
            for (int c = 0; c < 4; c++) {
                sc[c] = (f32x4){0.f, 0.f, 0.f, 0.f};
#pragma unroll
                for (int s = 0; s < 4; s++) {
                    int row = c * 16 + t15;
                    int ck = (s * 4 + t4) ^ (row & 7);
                    short8 kf = *(short8*)(&Kls[buf][row * 128 + ck * 8]);
                    sc[c] = __builtin_amdgcn_mfma_f32_16x16x32_bf16(kf, qf[s], sc[c], 0, 0, 0);
                }
            }

            if (t * 64 + 63 > q0w) {
                int qq = q0w + t15;
#pragma unroll
                for (int c = 0; c < 4; c++)
#pragma unroll
                    for (int r = 0; r < 4; r++) {
                        int kv = t * 64 + c * 16 + t4 * 4 + r;
                        if (kv > qq) sc[c][r] = -1e30f;
                    }
            }

            float tm = fmaxf(fmaxf(fmaxf(sc[0][0], sc[0][1]), fmaxf(sc[0][2], sc[0][3])),
                             fmaxf(fmaxf(sc[1][0], sc[1][1]), fmaxf(sc[1][2], sc[1][3])));
            tm = fmaxf(tm, fmaxf(fmaxf(fmaxf(sc[2][0], sc[2][1]), fmaxf(sc[2][2], sc[2][3])),
                                 fmaxf(fmaxf(sc[3][0], sc[3][1]), fmaxf(sc[3][2], sc[3][3]))));
            bool need = (tm > m_s + 8.f);
            if (__any(need)) {
                tm = fmaxf(tm, __shfl_xor(tm, 16));
                tm = fmaxf(tm, __shfl_xor(tm, 32));
                float mn = fmaxf(m_s, tm);
                float scf = exp2f(m_s - mn);
                m_s = mn;
                l_s *= scf;
                float sr0 = __shfl(scf, t4 * 4 + 0);
                float sr1 = __shfl(scf, t4 * 4 + 1);
                float sr2 = __shfl(scf, t4 * 4 + 2);
                float sr3 = __shfl(scf, t4 * 4 + 3);
#pragma unroll
                for (int st = 0; st < 8; st++) {
                    o[st][0] *= sr0; o[st][1] *= sr1;
                    o[st][2] *= sr2; o[st][3] *= sr3;
                }
            }
            int t15l = t15 & 7;
#pragma unroll
            for (int c = 0; c < 4; c++) {
                float p0 = exp2f(sc[c][0] - m_s);
                float p1 = exp2f(sc[c][1] - m_s);
                float p2 = exp2f(sc[c][2] - m_s);
                float p3 = exp2f(sc[c][3] - m_s);
                l_s += (p0 + p1) + (p2 + p3);
                unsigned u0, u1;
                asm("v_cvt_pk_bf16_f32 %0, %1, %2" : "=v"(u0) : "v"(p0), "v"(p1));
                asm("v_cvt_pk_bf16_f32 %0, %1, %2" : "=v"(u1) : "v"(p2), "v"(p3));
                int ch = (c * 2 + (t4 >> 1)) ^ t15l;
                uint2 uu; uu.x = u0; uu.y = u1;
                *(uint2*)((char*)&Pls[wid][0] + t15 * 128 + ch * 16 + (t4 & 1) * 8) = uu;
            }
        }

        if (t + 1 < nt) asm volatile("s_waitcnt vmcnt(2)" ::: "memory");
        else            asm volatile("s_waitcnt vmcnt(0)" ::: "memory");
        __builtin_amdgcn_s_barrier();

        if (active) {
            short8 pa[2];
#pragma unroll
            for (int s2 = 0; s2 < 2; s2++) {
                int ch2 = (s2 * 4 + t4) ^ (t15 & 7);
                pa[s2] = *(short8*)((char*)&Pls[wid][0] + t15 * 128 + ch2 * 16);
            }
#pragma unroll
            for (int st = 0; st < 8; st++) {
#pragma unroll
                for (int s2 = 0; s2 < 2; s2++) {
                    int row = st * 16 + t15;
                    int ck = (s2 * 4 + t4) ^ (row & 7);
                    short8 vf = *(short8*)(&Vls[row * 64 + ck * 8]);
                    o[st] = __builtin_amdgcn_mfma_f32_16x16x32_bf16(pa[s2], vf, o[st], 0, 0, 0);
                }
            }
        }

        asm volatile("s_waitcnt vmcnt(0)" ::: "memory");
        __builtin_amdgcn_s_barrier();
    }

    l_s += __shfl_xor(l_s, 16);
    l_s += __shfl_xor(l_s, 32);
    float lr0 = __shfl(l_s, t4 * 4 + 0);
    float lr1 = __shfl(l_s, t4 * 4 + 1);
    float lr2 = __shfl(l_s, t4 * 4 + 2);
    float lr3 = __shfl(l_s, t4 * 4 + 3);
    float lr[4] = {lr0, lr1, lr2, lr3};

    int b = z >> 4, h = z & 15;
#pragma unroll
    for (int st = 0; st < 8; st++)
#pragma unroll
        for (int r = 0; r < 4; r++) {
            int s = q0w + t4 * 4 + r;
            float val = o[st][r] / lr[r];
            O[((size_t)b * 2048 + s) * 2048 + h * 128 + st * 16 + t15] = f2bf(val);
        }
}

extern "C" void kernel_launch(void* const* d_in, const int* in_sizes, int n_in,
                              void* d_out, int out_size, void* d_ws, size_t ws_size,
                              hipStream_t stream) {
    const float* x = (const float*)d_in[0];      // (4,2048,2048)
    const float* Wqkv = (const float*)d_in[1];   // (2048,6144)
    const float* Wo = (const float*)d_in[2];     // (2048,2048)

    const int B = 4, S = 2048, D = 2048, DK = 128;
    const int M = B * S;          // 8192
    const int N1 = 3 * D;         // 6144
    (void)in_sizes; (void)n_in; (void)out_size; (void)ws_size;

    char* ws = (char*)d_ws;
    size_t off = 0;
    short* x_bf = (short*)(ws + off);   off += (size_t)M * D * 2;
    short* wqkv_t = (short*)(ws + off); off += (size_t)N1 * D * 2;
    short* wo_t = (short*)(ws + off);   off += (size_t)D * D * 2;
    short* Qb = (short*)(ws + off);     off += (size_t)64 * S * DK * 2;
    short* Kb = (short*)(ws + off);     off += (size_t)64 * S * DK * 2;
    short* Vt = (short*)(ws + off);     off += (size_t)64 * S * DK * 2;
    short* Ob = (short*)(ws + off);     off += (size_t)M * D * 2;

    // 1. x -> bf16
    cvt_f32_to_bf16<<<(M * D / 4 + 255) / 256, 256, 0, stream>>>(x, x_bf, M * D / 4);
    // 2. Wqkv^T -> bf16 (N1 x D)
    transpose_to_bf16<<<dim3(D / 64, N1 / 64, 1), 256, 0, stream>>>(Wqkv, wqkv_t, D, N1);
    // 3. Wo^T -> bf16 (D x D)
    transpose_to_bf16<<<dim3(D / 64, D / 64, 1), 256, 0, stream>>>(Wo, wo_t, D, D);
    // 4. GEMM1: qkv = x @ Wqkv -> Q(scaled 1/(sqrt(128)ln2))/K/V^T  (256² depth-3, 768 blocks)
    gemm256<0><<<(M / 256) * (N1 / 256), 512, 0, stream>>>(
        x_bf, wqkv_t, M, N1, D, Qb, Kb, Vt, nullptr, 0.12751743553366927f);
    // 5. attention (paired panels + counted-vmcnt barriers)
    attn_fwd<<<dim3(16, 64), 512, 0, stream>>>(Qb, Kb, Vt, Ob);
    // 6. GEMM2: out = O @ Wo (f32)   (256² depth-3, 256 blocks)
    gemm256<1><<<(M / 256) * (D / 256), 512, 0, stream>>>(
        Ob, wo_t, M, D, D, nullptr, nullptr, nullptr, (float*)d_out, 1.0f);
}